// Round 7
// baseline (167.383 us; speedup 1.0000x reference)
//
#include <hip/hip_runtime.h>

#define NB 2
#define NH 8
#define NS 2048
#define ND 64
#define QBLK 64
#define KBLK 64
#define NT (NS / KBLK)    // 32
#define QST 68            // Q LDS row stride (f16)
#define KST 76            // K LDS row stride
#define VST 70            // VT row stride
#define PST 68            // P row stride

typedef _Float16 f16x4 __attribute__((ext_vector_type(4)));
typedef _Float16 f16x8 __attribute__((ext_vector_type(8)));
typedef float    f32x4 __attribute__((ext_vector_type(4)));

#define MFMA16(A,B,C) __builtin_amdgcn_mfma_f32_16x16x32_f16((A),(B),(C),0,0,0)

static __device__ __forceinline__ f16x8 cat8(f16x4 a, f16x4 b) {
    return __builtin_shufflevector(a, b, 0, 1, 2, 3, 4, 5, 6, 7);
}
static __device__ __forceinline__ f16x8 lds8(const _Float16* p) {
    f16x4 a = *(const f16x4*)p;          // ds_read_b64 pair
    f16x4 b = *(const f16x4*)(p + 4);
    return cat8(a, b);
}
// dbuf barrier: my LDS ops drained, rendezvous; no vmcnt drain
static __device__ __forceinline__ void barw() {
    asm volatile("s_waitcnt lgkmcnt(0)" ::: "memory");
    __builtin_amdgcn_sched_barrier(0);
    __builtin_amdgcn_s_barrier();
    __builtin_amdgcn_sched_barrier(0);
}

__global__ __launch_bounds__(256, 2)
void sdpa_kernel(const float* __restrict__ Qg, const float* __restrict__ Kg,
                 const float* __restrict__ Vg, float* __restrict__ Og,
                 float* __restrict__ Ag)
{
    const int tid  = threadIdx.x;
    const int w    = tid >> 6;
    const int lane = tid & 63;
    const int lg   = lane >> 4;
    const int lc   = lane & 15;

    // XCD-pinned decode: consecutive block ids round-robin the 8 XCDs,
    // so bid&7 selects the XCD; give each XCD 2 heads -> K/V L2-resident.
    const int bid = blockIdx.x;
    const int xcd = bid & 7;
    const int j   = bid >> 3;           // 0..63
    const int bh  = 2 * xcd + (j >> 5); // 0..15
    const int qt  = j & 31;             // 0..31

    const size_t base = (size_t)bh * NS * ND;
    const float* Qp = Qg + base + (size_t)qt * QBLK * ND;
    const float* Kp = Kg + base;
    const float* Vp = Vg + base;
    float*       Op = Og + base + (size_t)qt * QBLK * ND;
    float*       Ap = Ag + (size_t)bh * NS * NS + (size_t)qt * QBLK * NS;

    // pool: Ks0 9728 | Ks1 9728 | VT0 8960 | VT1 8960 | union(Qs,Ps) 8704 = 46080 B
    __shared__ __align__(16) unsigned char pool[46080];
    _Float16* Ks0 = (_Float16*)pool;
    _Float16* Ks1 = (_Float16*)(pool + 9728);
    _Float16* VT0 = (_Float16*)(pool + 19456);
    _Float16* VT1 = (_Float16*)(pool + 28416);
    _Float16* Qs  = (_Float16*)(pool + 37376);   // dead after qf loads
    _Float16* Ps  = (_Float16*)(pool + 37376);   // overlays Qs in pass B

    const int srow = tid >> 4;          // 0..15
    const int sd0  = (tid & 15) * 4;    // 0..60
    const int kq2  = tid >> 4;          // 0..15 (V: key quad 4*kq2)
    const int dg2  = tid & 15;          // 0..15 (V: d quad 4*dg2)

    // ---- stage Q (scaled by 1/T = 1/8, exact) ----
    #pragma unroll
    for (int it = 0; it < 4; ++it) {
        const int r = srow + 16 * it;
        float4 f = *(const float4*)&Qp[(size_t)r * ND + sd0];
        f16x4 h = { (_Float16)(f.x * 0.125f), (_Float16)(f.y * 0.125f),
                    (_Float16)(f.z * 0.125f), (_Float16)(f.w * 0.125f) };
        *(f16x4*)&Qs[r * QST + sd0] = h;
    }
    __syncthreads();

    const int q = 16 * w + lc;
    const f16x8 qf0 = lds8(&Qs[q * QST + 8 * lg]);
    const f16x8 qf1 = lds8(&Qs[q * QST + 8 * lg + 32]);
    __syncthreads();   // Qs reads done before Ps overlay (pass B)

    float4 kA[4], kB[4], vA[4], vB[4];

    auto loadK = [&](float4 (&d)[4], int t) {
        #pragma unroll
        for (int it = 0; it < 4; ++it)
            d[it] = *(const float4*)&Kp[(size_t)(t * KBLK + srow + 16 * it) * ND + sd0];
    };
    auto writeK = [&](const float4 (&s)[4], _Float16* ks) {
        #pragma unroll
        for (int it = 0; it < 4; ++it) {
            f16x4 h = { (_Float16)s[it].x, (_Float16)s[it].y,
                        (_Float16)s[it].z, (_Float16)s[it].w };
            *(f16x4*)&ks[(srow + 16 * it) * KST + sd0] = h;
        }
    };
    auto loadV = [&](float4 (&d)[4], int t) {   // rows 4kq2..+3, d 4dg2..+3 (coalesced)
        #pragma unroll
        for (int r = 0; r < 4; ++r)
            d[r] = *(const float4*)&Vp[(size_t)(t * KBLK + 4 * kq2 + r) * ND + 4 * dg2];
    };
    auto writeVT = [&](const float4 (&s)[4], _Float16* vt) { // 4x4 reg transpose -> b64
        #pragma unroll
        for (int jj = 0; jj < 4; ++jj) {
            f16x4 col = { (_Float16)s[0][jj], (_Float16)s[1][jj],
                          (_Float16)s[2][jj], (_Float16)s[3][jj] };
            *(f16x4*)&vt[(4 * dg2 + jj) * VST + 4 * kq2] = col;
        }
    };

    float lacc = 0.0f;   // per-lane partial sum of exp(s) (max-free softmax)

    auto computeA = [&](const _Float16* ks) {
        f32x4 s[4];
        __builtin_amdgcn_s_setprio(1);
        #pragma unroll
        for (int mt = 0; mt < 4; ++mt) {
            f16x8 a0 = lds8(&ks[(16 * mt + lc) * KST + 8 * lg]);
            f16x8 a1 = lds8(&ks[(16 * mt + lc) * KST + 8 * lg + 32]);
            f32x4 z = {0.f, 0.f, 0.f, 0.f};
            z = MFMA16(a0, qf0, z);
            z = MFMA16(a1, qf1, z);
            s[mt] = z;
        }
        __builtin_amdgcn_s_setprio(0);
        #pragma unroll
        for (int mt = 0; mt < 4; ++mt)
            #pragma unroll
            for (int r = 0; r < 4; ++r)
                lacc += __expf(s[mt][r]);
    };

    // ================= PASS A: denominator (one barrier per tile) =================
    loadK(kA, 0);
    writeK(kA, Ks0);
    loadK(kB, 1);
    barw();
    for (int t = 0; t < NT; t += 2) {
        const int n2 = (t + 2 < NT) ? t + 2 : 0;
        loadK(kA, n2);           // prefetch t+2
        writeK(kB, Ks1);         // stage t+1
        computeA(Ks0);           // consume t
        barw();
        const int n3 = (t + 3 < NT) ? t + 3 : 0;
        loadK(kB, n3);
        writeK(kA, Ks0);
        computeA(Ks1);
        barw();
    }
    // deferred reduce over lg groups (lane bits 4,5)
    lacc += __shfl_xor(lacc, 16);
    lacc += __shfl_xor(lacc, 32);
    const float il = 1.0f / lacc;

    // ================= PASS B: attn write + PV =================
    f32x4 acc[4];
    #pragma unroll
    for (int dt = 0; dt < 4; ++dt) acc[dt] = {0.f, 0.f, 0.f, 0.f};

    auto computeB = [&](const _Float16* ks, const _Float16* vt, int t) {
        f32x4 s[4];
        __builtin_amdgcn_s_setprio(1);
        #pragma unroll
        for (int mt = 0; mt < 4; ++mt) {
            f16x8 a0 = lds8(&ks[(16 * mt + lc) * KST + 8 * lg]);
            f16x8 a1 = lds8(&ks[(16 * mt + lc) * KST + 8 * lg + 32]);
            f32x4 z = {0.f, 0.f, 0.f, 0.f};
            z = MFMA16(a0, qf0, z);
            z = MFMA16(a1, qf1, z);
            s[mt] = z;
        }
        __builtin_amdgcn_s_setprio(0);
        #pragma unroll
        for (int mt = 0; mt < 4; ++mt) {
            f32x4 p;
            #pragma unroll
            for (int r = 0; r < 4; ++r)
                p[r] = __expf(s[mt][r]) * il;
            __builtin_nontemporal_store(
                p, (f32x4*)&Ap[(size_t)q * NS + t * KBLK + 16 * mt + 4 * lg]);
            f16x4 ph = { (_Float16)p[0], (_Float16)p[1],
                         (_Float16)p[2], (_Float16)p[3] };
            *(f16x4*)&Ps[q * PST + 16 * mt + 4 * lg] = ph;
        }
        asm volatile("s_waitcnt lgkmcnt(0)" ::: "memory");  // wave-private P rows
        __builtin_amdgcn_sched_barrier(0);
        f16x8 bf0 = lds8(&Ps[q * PST + 8 * lg]);
        f16x8 bf1 = lds8(&Ps[q * PST + 32 + 8 * lg]);
        __builtin_amdgcn_s_setprio(1);
        #pragma unroll
        for (int dt = 0; dt < 4; ++dt) {
            f16x8 af0 = lds8(&vt[(16 * dt + lc) * VST + 8 * lg]);
            f16x8 af1 = lds8(&vt[(16 * dt + lc) * VST + 32 + 8 * lg]);
            acc[dt] = MFMA16(af0, bf0, acc[dt]);
            acc[dt] = MFMA16(af1, bf1, acc[dt]);
        }
        __builtin_amdgcn_s_setprio(0);
    };

    loadK(kA, 0); loadV(vA, 0);
    writeK(kA, Ks0); writeVT(vA, VT0);
    loadK(kB, 1); loadV(vB, 1);
    barw();
    for (int t = 0; t < NT; t += 2) {
        const int n2 = (t + 2 < NT) ? t + 2 : 0;
        loadK(kA, n2); loadV(vA, n2);
        writeK(kB, Ks1); writeVT(vB, VT1);
        computeB(Ks0, VT0, t);
        barw();
        const int n3 = (t + 3 < NT) ? t + 3 : 0;
        loadK(kB, n3); loadV(vB, n3);
        writeK(kA, Ks0); writeVT(vA, VT0);
        computeB(Ks1, VT1, t + 1);
        barw();
    }

    // O^T[d = 16dt+4lg+r][q] -> Op[q][d]
    #pragma unroll
    for (int dt = 0; dt < 4; ++dt)
        __builtin_nontemporal_store(
            acc[dt], (f32x4*)&Op[(size_t)q * ND + 16 * dt + 4 * lg]);
}

extern "C" void kernel_launch(void* const* d_in, const int* in_sizes, int n_in,
                              void* d_out, int out_size, void* d_ws, size_t ws_size,
                              hipStream_t stream) {
    const float* q = (const float*)d_in[0];
    const float* k = (const float*)d_in[1];
    const float* v = (const float*)d_in[2];
    float* out  = (float*)d_out;
    float* attn = out + (size_t)NB * NH * NS * ND;  // outputs: (output, attn)

    sdpa_kernel<<<dim3((NS / QBLK) * NB * NH), 256, 0, stream>>>(q, k, v, out, attn);
}